// Round 1
// baseline (246.595 us; speedup 1.0000x reference)
//
#include <hip/hip_runtime.h>
#include <cstdint>
#include <cstddef>

#define T_TOK 32768
#define DM 768
#define EDIM 192
#define NEXP 8

typedef unsigned short u16;
typedef short bf16x8 __attribute__((ext_vector_type(8)));
typedef float f32x4 __attribute__((ext_vector_type(4)));
typedef u16 u16x8 __attribute__((ext_vector_type(8)));

__device__ __forceinline__ u16 f2bf(float f) {
  unsigned u = __float_as_uint(f);
  return (u16)((u + 0x7FFFu + ((u >> 16) & 1u)) >> 16);  // RNE
}
__device__ __forceinline__ float bf2f(u16 u) {
  return __uint_as_float(((unsigned)u) << 16);
}

// Read one MFMA fragment (8 bf16) from a swizzled LDS tile with 128-byte rows.
// Swizzle: phys_byte = row*128 + (kb ^ ((row&7)<<4))
__device__ __forceinline__ bf16x8 frag_ld(const u16* lds, int row, int kb) {
  int ph = row * 128 + (kb ^ ((row & 7) << 4));
  return *(const bf16x8*)((const char*)lds + ph);
}

// ---------------------------------------------------------------------------
// Weight transpose + fp32->bf16:  in [R][C] -> out [C][R]
// mat 0: W1 (768x192), 1: W3 (768x192), 2: W2 (192x768)
// ---------------------------------------------------------------------------
__global__ __launch_bounds__(256) void k_prep(
    const float* __restrict__ W1, const float* __restrict__ W3,
    const float* __restrict__ W2, u16* __restrict__ W1T,
    u16* __restrict__ W3T, u16* __restrict__ W2T)
{
  __shared__ __align__(16) float td[64][68];
  const int z = blockIdx.z;
  const int mat = z >> 3, e = z & 7;
  const int R = (mat == 2) ? EDIM : DM;
  const int C = (mat == 2) ? DM : EDIM;
  const int r0 = blockIdx.x * 64, c0 = blockIdx.y * 64;
  if (r0 >= R || c0 >= C) return;
  const float* in = (mat == 0 ? W1 : mat == 1 ? W3 : W2) + (size_t)e * R * C;
  u16* out = (mat == 0 ? W1T : mat == 1 ? W3T : W2T) + (size_t)e * R * C;
  const int tid = threadIdx.x;
  {
    int rl = tid >> 2, cs = (tid & 3) * 16;
    const float* s = in + (size_t)(r0 + rl) * C + c0 + cs;
    #pragma unroll
    for (int i = 0; i < 16; i += 4) *(float4*)&td[rl][cs + i] = *(const float4*)(s + i);
  }
  __syncthreads();
  {
    int cl = tid >> 2, rs = (tid & 3) * 16;
    u16* d = out + (size_t)(c0 + cl) * R + r0 + rs;
    u16x8 o0, o1;
    #pragma unroll
    for (int i = 0; i < 8; ++i) {
      o0[i] = f2bf(td[rs + i][cl]);
      o1[i] = f2bf(td[rs + 8 + i][cl]);
    }
    *(u16x8*)d = o0;
    *(u16x8*)(d + 8) = o1;
  }
}

// ---------------------------------------------------------------------------
// Tokenize (NCHW -> token-major bf16) + fp32 router + top-2 + expert lists
// 64 tokens per block (same b, two h-rows), 256 threads.
// ---------------------------------------------------------------------------
__global__ __launch_bounds__(256) void k_tokrouter(
    const float* __restrict__ x, const float* __restrict__ Wr,
    u16* __restrict__ tokbf, int* __restrict__ cnt,
    int* __restrict__ toklist, float* __restrict__ gatelist)
{
  __shared__ __align__(16) float tokL[64][64];   // [c][t]
  __shared__ float WrL[8][64];
  __shared__ float logitsL[64][8];
  __shared__ int cnt8[8];
  __shared__ int baseL[8];
  const int tid = threadIdx.x;
  const int t0 = blockIdx.x * 64;
  const int b = t0 >> 10;
  const int h0 = (t0 >> 5) & 31;
  const float* xb = x + (size_t)b * (DM * 1024);

  const int tr = tid & 63;   // router token
  const int ep = tid >> 6;   // router expert (ep and ep+4)
  float l0 = 0.f, l1 = 0.f;

  for (int cb = 0; cb < 12; ++cb) {
    const int c0 = cb * 64;
    __syncthreads();
    // Wr chunk [8][64]
    {
      int f = tid;
      #pragma unroll
      for (int it = 0; it < 2; ++it, f += 256)
        WrL[f >> 6][f & 63] = Wr[(f >> 6) * DM + c0 + (f & 63)];
    }
    // x chunk -> LDS [64c][64t]
    {
      int cl = tid >> 2;
      int ts = (tid & 3) * 16;
      int hh = h0 + (ts >> 5), ww = ts & 31;
      const float* src = xb + ((size_t)(c0 + cl) * 32 + hh) * 32 + ww;
      float* d = &tokL[cl][ts];
      #pragma unroll
      for (int i = 0; i < 16; i += 4) *(float4*)(d + i) = *(const float4*)(src + i);
    }
    __syncthreads();
    // router accumulate (fp32)
    for (int c = 0; c < 64; ++c) {
      float tv = tokL[c][tr];
      l0 = fmaf(tv, WrL[ep][c], l0);
      l1 = fmaf(tv, WrL[ep + 4][c], l1);
    }
    // token-major bf16 write
    {
      int tl = tid >> 2;
      int cs = (tid & 3) * 16;
      u16x8 o0, o1;
      #pragma unroll
      for (int i = 0; i < 8; ++i) {
        o0[i] = f2bf(tokL[cs + i][tl]);
        o1[i] = f2bf(tokL[cs + 8 + i][tl]);
      }
      u16* d = tokbf + (size_t)(t0 + tl) * DM + c0 + cs;
      *(u16x8*)d = o0;
      *(u16x8*)(d + 8) = o1;
    }
  }

  logitsL[tr][ep] = l0;
  logitsL[tr][ep + 4] = l1;
  if (tid < 8) cnt8[tid] = 0;
  __syncthreads();

  int e0 = -1, e1 = -1, lp0 = 0, lp1 = 0;
  float g0 = 0.f, g1 = 0.f;
  if (tid < 64) {
    float v0 = -1e30f, v1 = -1e30f;
    #pragma unroll
    for (int e = 0; e < 8; ++e) { float v = logitsL[tid][e]; if (v > v0) { v0 = v; e0 = e; } }
    #pragma unroll
    for (int e = 0; e < 8; ++e) {
      if (e == e0) continue;
      float v = logitsL[tid][e]; if (v > v1) { v1 = v; e1 = e; }
    }
    float w = expf(v1 - v0);            // v0 >= v1
    g0 = 1.f / (1.f + w);
    g1 = w / (1.f + w);
    lp0 = atomicAdd(&cnt8[e0], 1);
    lp1 = atomicAdd(&cnt8[e1], 1);
  }
  __syncthreads();
  if (tid < 8) baseL[tid] = atomicAdd(&cnt[tid], cnt8[tid]);
  __syncthreads();
  if (tid < 64) {
    int tg = t0 + tid;
    int p0 = baseL[e0] + lp0;
    int p1 = baseL[e1] + lp1;
    toklist[e0 * T_TOK + p0] = tg;              // k=0 slot
    gatelist[e0 * T_TOK + p0] = g0;
    toklist[e1 * T_TOK + p1] = tg | (1 << 16);  // k=1 slot
    gatelist[e1 * T_TOK + p1] = g1;
  }
}

__global__ void k_prefix(const int* __restrict__ cnt, int* __restrict__ offs) {
  if (threadIdx.x == 0) {
    int s = 0;
    for (int e = 0; e < NEXP; ++e) { offs[e] = s; s += cnt[e]; }
    offs[NEXP] = s;
  }
}

// ---------------------------------------------------------------------------
// Stage 1: h = silu(tok @ W1) * (tok @ W3), grouped by expert.
// Tile: 128 tokens x 64 hidden, BK=64, 4 waves (2M x 2N).
// ---------------------------------------------------------------------------
__global__ __launch_bounds__(256) void k_ffn1(
    const u16* __restrict__ tokbf, const u16* __restrict__ W1T,
    const u16* __restrict__ W3T, const int* __restrict__ cnt,
    const int* __restrict__ offs, const int* __restrict__ toklist,
    u16* __restrict__ hbuf)
{
  __shared__ __align__(16) u16 As[128 * 64];
  __shared__ __align__(16) u16 B1s[64 * 64];
  __shared__ __align__(16) u16 B3s[64 * 64];
  __shared__ int rowbaseL[128];
  const int e = blockIdx.z;
  const int count = cnt[e];
  const int start = blockIdx.x * 128;
  if (start >= count) return;
  const int n0 = blockIdx.y * 64;
  const int rows = min(128, count - start);
  const int tid = threadIdx.x;

  if (tid < 128) {
    int r = (tid < rows) ? tid : 0;
    rowbaseL[tid] = (toklist[e * T_TOK + start + r] & 0xFFFF) * DM;
  }
  __syncthreads();

  const int w = tid >> 6, l = tid & 63;
  const int wm = (w >> 1) * 64, wn = (w & 1) * 32;
  const int lr = l & 15;
  const int lk = (l >> 4) * 16;

  f32x4 acc1[4][2], acc3[4][2];
  #pragma unroll
  for (int i = 0; i < 4; ++i)
    #pragma unroll
    for (int j = 0; j < 2; ++j) {
      acc1[i][j] = (f32x4){0.f, 0.f, 0.f, 0.f};
      acc3[i][j] = (f32x4){0.f, 0.f, 0.f, 0.f};
    }

  for (int kc = 0; kc < 12; ++kc) {
    #pragma unroll
    for (int it = 0; it < 4; ++it) {  // A: 128 rows x 128B
      int idx = it * 256 + tid;
      int r = idx >> 3, s = idx & 7;
      int sw = (s * 16) ^ ((r & 7) << 4);
      const u16* src = tokbf + rowbaseL[r] + kc * 64 + (sw >> 1);
      *(u16x8*)((char*)As + idx * 16) = *(const u16x8*)src;
    }
    #pragma unroll
    for (int it = 0; it < 2; ++it) {  // B: 64 rows x 128B each
      int idx = it * 256 + tid;
      int r = idx >> 3, s = idx & 7;
      int sw = (s * 16) ^ ((r & 7) << 4);
      size_t wb = (size_t)(e * EDIM + n0 + r) * DM + kc * 64 + (sw >> 1);
      *(u16x8*)((char*)B1s + idx * 16) = *(const u16x8*)(W1T + wb);
      *(u16x8*)((char*)B3s + idx * 16) = *(const u16x8*)(W3T + wb);
    }
    __syncthreads();
    #pragma unroll
    for (int kk = 0; kk < 2; ++kk) {
      const int kb = kk * 64 + lk;
      bf16x8 af[4], b1[2], b3[2];
      #pragma unroll
      for (int mf = 0; mf < 4; ++mf) af[mf] = frag_ld(As, wm + mf * 16 + lr, kb);
      #pragma unroll
      for (int nf = 0; nf < 2; ++nf) {
        b1[nf] = frag_ld(B1s, wn + nf * 16 + lr, kb);
        b3[nf] = frag_ld(B3s, wn + nf * 16 + lr, kb);
      }
      #pragma unroll
      for (int mf = 0; mf < 4; ++mf)
        #pragma unroll
        for (int nf = 0; nf < 2; ++nf) {
          acc1[mf][nf] = __builtin_amdgcn_mfma_f32_16x16x32_bf16(af[mf], b1[nf], acc1[mf][nf], 0, 0, 0);
          acc3[mf][nf] = __builtin_amdgcn_mfma_f32_16x16x32_bf16(af[mf], b3[nf], acc3[mf][nf], 0, 0, 0);
        }
    }
    __syncthreads();
  }

  const int rq = (l >> 4) * 4;
  const int abase = offs[e] + start;
  #pragma unroll
  for (int mf = 0; mf < 4; ++mf)
    #pragma unroll
    for (int nf = 0; nf < 2; ++nf)
      #pragma unroll
      for (int r = 0; r < 4; ++r) {
        int m = wm + mf * 16 + rq + r;
        if (m < rows) {
          float a = acc1[mf][nf][r];
          float hv = (a / (1.f + expf(-a))) * acc3[mf][nf][r];
          hbuf[(size_t)(abase + m) * EDIM + (n0 + wn + nf * 16 + lr)] = f2bf(hv);
        }
      }
}

// ---------------------------------------------------------------------------
// Stage 2: ypart[k][t][:] = gate * (h @ W2[e]), grouped by expert.
// Tile: 128 rows x 128 cols, K=192 (3 chunks), 4 waves (2x2).
// ---------------------------------------------------------------------------
__global__ __launch_bounds__(256) void k_ffn2(
    const u16* __restrict__ hbuf, const u16* __restrict__ W2T,
    const int* __restrict__ cnt, const int* __restrict__ offs,
    const int* __restrict__ toklist, const float* __restrict__ gatelist,
    u16* __restrict__ ypart)
{
  __shared__ __align__(16) u16 As[128 * 64];
  __shared__ __align__(16) u16 Bs[128 * 64];
  __shared__ int dstL[128];
  __shared__ float gL[128];
  const int e = blockIdx.z;
  const int count = cnt[e];
  const int start = blockIdx.x * 128;
  if (start >= count) return;
  const int n0 = blockIdx.y * 128;
  const int rows = min(128, count - start);
  const int tid = threadIdx.x;
  const int abase = offs[e] + start;

  if (tid < 128) {
    int r = (tid < rows) ? tid : 0;
    int entry = toklist[e * T_TOK + start + r];
    int t = entry & 0xFFFF, k = entry >> 16;
    dstL[tid] = (k * T_TOK + t) * DM;
    gL[tid] = gatelist[e * T_TOK + start + r];
  }
  __syncthreads();

  const int w = tid >> 6, l = tid & 63;
  const int wm = (w >> 1) * 64, wn = (w & 1) * 64;
  const int lr = l & 15;
  const int lk = (l >> 4) * 16;

  f32x4 acc[4][4];
  #pragma unroll
  for (int i = 0; i < 4; ++i)
    #pragma unroll
    for (int j = 0; j < 4; ++j) acc[i][j] = (f32x4){0.f, 0.f, 0.f, 0.f};

  for (int kc = 0; kc < 3; ++kc) {
    #pragma unroll
    for (int it = 0; it < 4; ++it) {
      int idx = it * 256 + tid;
      int r = idx >> 3, s = idx & 7;
      int sw = (s * 16) ^ ((r & 7) << 4);
      int rr = (r < rows) ? r : 0;
      const u16* sa = hbuf + (size_t)(abase + rr) * EDIM + kc * 64 + (sw >> 1);
      *(u16x8*)((char*)As + idx * 16) = *(const u16x8*)sa;
      const u16* sb = W2T + (size_t)(e * DM + n0 + r) * EDIM + kc * 64 + (sw >> 1);
      *(u16x8*)((char*)Bs + idx * 16) = *(const u16x8*)sb;
    }
    __syncthreads();
    #pragma unroll
    for (int kk = 0; kk < 2; ++kk) {
      const int kb = kk * 64 + lk;
      bf16x8 af[4], bf_[4];
      #pragma unroll
      for (int mf = 0; mf < 4; ++mf) af[mf] = frag_ld(As, wm + mf * 16 + lr, kb);
      #pragma unroll
      for (int nf = 0; nf < 4; ++nf) bf_[nf] = frag_ld(Bs, wn + nf * 16 + lr, kb);
      #pragma unroll
      for (int mf = 0; mf < 4; ++mf)
        #pragma unroll
        for (int nf = 0; nf < 4; ++nf)
          acc[mf][nf] = __builtin_amdgcn_mfma_f32_16x16x32_bf16(af[mf], bf_[nf], acc[mf][nf], 0, 0, 0);
    }
    __syncthreads();
  }

  const int rq = (l >> 4) * 4;
  #pragma unroll
  for (int mf = 0; mf < 4; ++mf)
    #pragma unroll
    for (int nf = 0; nf < 4; ++nf)
      #pragma unroll
      for (int r = 0; r < 4; ++r) {
        int m = wm + mf * 16 + rq + r;
        if (m < rows) {
          float v = acc[mf][nf][r] * gL[m];
          ypart[(size_t)dstL[m] + (n0 + wn + nf * 16 + lr)] = f2bf(v);
        }
      }
}

// ---------------------------------------------------------------------------
// LayerNorm(y0+y1) + residual(x), write NCHW. 64 tokens/block.
// ---------------------------------------------------------------------------
__global__ __launch_bounds__(256) void k_ln(
    const u16* __restrict__ ypart, const float* __restrict__ x,
    const float* __restrict__ gamma, const float* __restrict__ beta,
    float* __restrict__ out)
{
  __shared__ float lnT[64][65];
  __shared__ float muL[64], rsL[64];
  const int tid = threadIdx.x;
  const int t0 = blockIdx.x * 64;
  const int b = t0 >> 10;
  const int h0 = (t0 >> 5) & 31;
  const u16* y0 = ypart;
  const u16* y1 = ypart + (size_t)T_TOK * DM;
  const int tl = tid >> 2, q = tid & 3;
  const size_t tbase = (size_t)(t0 + tl) * DM;

  float sum = 0.f, sq = 0.f;
  for (int jj = 0; jj < 12; ++jj) {
    int c = jj * 64 + q * 16;
    u16x8 a0 = *(const u16x8*)(y0 + tbase + c);
    u16x8 a1 = *(const u16x8*)(y0 + tbase + c + 8);
    u16x8 b0 = *(const u16x8*)(y1 + tbase + c);
    u16x8 b1 = *(const u16x8*)(y1 + tbase + c + 8);
    #pragma unroll
    for (int i = 0; i < 8; ++i) {
      float v = bf2f(a0[i]) + bf2f(b0[i]); sum += v; sq += v * v;
      float u = bf2f(a1[i]) + bf2f(b1[i]); sum += u; sq += u * u;
    }
  }
  sum += __shfl_xor(sum, 1); sq += __shfl_xor(sq, 1);
  sum += __shfl_xor(sum, 2); sq += __shfl_xor(sq, 2);
  float mu = sum * (1.f / 768.f);
  float var = sq * (1.f / 768.f) - mu * mu;
  float rs = 1.0f / sqrtf(var + 1e-5f);
  if (q == 0) { muL[tl] = mu; rsL[tl] = rs; }
  __syncthreads();

  for (int cb = 0; cb < 12; ++cb) {
    const int c0 = cb * 64;
    if (cb) __syncthreads();
    {
      float mu_ = muL[tl], rs_ = rsL[tl];
      int c = c0 + q * 16;
      u16x8 a0 = *(const u16x8*)(y0 + tbase + c);
      u16x8 a1 = *(const u16x8*)(y0 + tbase + c + 8);
      u16x8 b0 = *(const u16x8*)(y1 + tbase + c);
      u16x8 b1 = *(const u16x8*)(y1 + tbase + c + 8);
      #pragma unroll
      for (int i = 0; i < 8; ++i) {
        float v = bf2f(a0[i]) + bf2f(b0[i]);
        lnT[q * 16 + i][tl] = (v - mu_) * rs_ * gamma[c + i] + beta[c + i];
        float u = bf2f(a1[i]) + bf2f(b1[i]);
        lnT[q * 16 + 8 + i][tl] = (u - mu_) * rs_ * gamma[c + 8 + i] + beta[c + 8 + i];
      }
    }
    __syncthreads();
    {
      int cl = tid >> 2, ts = (tid & 3) * 16;
      int c = c0 + cl;
      int hh = h0 + (ts >> 5), ww = ts & 31;
      size_t oidx = (((size_t)b * DM + c) * 32 + hh) * 32 + ww;
      #pragma unroll
      for (int i = 0; i < 16; i += 4) {
        float4 xv = *(const float4*)(x + oidx + i);
        float4 ov;
        ov.x = lnT[cl][ts + i + 0] + xv.x;
        ov.y = lnT[cl][ts + i + 1] + xv.y;
        ov.z = lnT[cl][ts + i + 2] + xv.z;
        ov.w = lnT[cl][ts + i + 3] + xv.w;
        *(float4*)(out + oidx + i) = ov;
      }
    }
  }
}

// ---------------------------------------------------------------------------
// Workspace layout (all 256-aligned); total ~185.3 MB
// ---------------------------------------------------------------------------
constexpr size_t OFF_TOK  = 0;
constexpr size_t OFF_W1T  = OFF_TOK + (size_t)T_TOK * DM * 2;
constexpr size_t OFF_W3T  = OFF_W1T + (size_t)NEXP * EDIM * DM * 2;
constexpr size_t OFF_W2T  = OFF_W3T + (size_t)NEXP * EDIM * DM * 2;
constexpr size_t OFF_H    = OFF_W2T + (size_t)NEXP * EDIM * DM * 2;
constexpr size_t OFF_YP   = OFF_H + (size_t)T_TOK * 2 * EDIM * 2;
constexpr size_t OFF_CNT  = OFF_YP + (size_t)2 * T_TOK * DM * 2;
constexpr size_t OFF_OFFS = OFF_CNT + 256;
constexpr size_t OFF_LIST = OFF_OFFS + 256;
constexpr size_t OFF_GATE = OFF_LIST + (size_t)NEXP * T_TOK * 4;

extern "C" void kernel_launch(void* const* d_in, const int* in_sizes, int n_in,
                              void* d_out, int out_size, void* d_ws, size_t ws_size,
                              hipStream_t stream) {
  const float* x     = (const float*)d_in[0];
  const float* Wr    = (const float*)d_in[1];
  const float* W1    = (const float*)d_in[2];
  const float* W3    = (const float*)d_in[3];
  const float* W2    = (const float*)d_in[4];
  const float* gamma = (const float*)d_in[5];
  const float* beta  = (const float*)d_in[6];
  float* out = (float*)d_out;
  char* ws = (char*)d_ws;

  u16* tokbf = (u16*)(ws + OFF_TOK);
  u16* W1T   = (u16*)(ws + OFF_W1T);
  u16* W3T   = (u16*)(ws + OFF_W3T);
  u16* W2T   = (u16*)(ws + OFF_W2T);
  u16* hbuf  = (u16*)(ws + OFF_H);
  u16* ypart = (u16*)(ws + OFF_YP);
  int* cnt   = (int*)(ws + OFF_CNT);
  int* offs  = (int*)(ws + OFF_OFFS);
  int* toklist = (int*)(ws + OFF_LIST);
  float* gatelist = (float*)(ws + OFF_GATE);

  hipMemsetAsync(cnt, 0, 64, stream);
  hipLaunchKernelGGL(k_prep, dim3(12, 12, 24), dim3(256), 0, stream,
                     W1, W3, W2, W1T, W3T, W2T);
  hipLaunchKernelGGL(k_tokrouter, dim3(512), dim3(256), 0, stream,
                     x, Wr, tokbf, cnt, toklist, gatelist);
  hipLaunchKernelGGL(k_prefix, dim3(1), dim3(64), 0, stream, cnt, offs);
  hipLaunchKernelGGL(k_ffn1, dim3(256, 3, 8), dim3(256), 0, stream,
                     tokbf, W1T, W3T, cnt, offs, toklist, hbuf);
  hipLaunchKernelGGL(k_ffn2, dim3(256, 6, 8), dim3(256), 0, stream,
                     hbuf, W2T, cnt, offs, toklist, gatelist, ypart);
  hipLaunchKernelGGL(k_ln, dim3(512), dim3(256), 0, stream,
                     ypart, x, gamma, beta, out);
}

// Round 2
// 238.350 us; speedup vs baseline: 1.0346x; 1.0346x over previous
//
#include <hip/hip_runtime.h>
#include <cstdint>
#include <cstddef>

#define T_TOK 32768
#define DM 768
#define EDIM 192
#define NEXP 8

typedef unsigned short u16;
typedef short bf16x8 __attribute__((ext_vector_type(8)));
typedef float f32x4 __attribute__((ext_vector_type(4)));
typedef u16 u16x8 __attribute__((ext_vector_type(8)));

__device__ __forceinline__ u16 f2bf(float f) {
  unsigned u = __float_as_uint(f);
  return (u16)((u + 0x7FFFu + ((u >> 16) & 1u)) >> 16);  // RNE
}
__device__ __forceinline__ float bf2f(u16 u) {
  return __uint_as_float(((unsigned)u) << 16);
}

// async global->LDS, 16B per lane. LDS dest must be wave-uniform base + lane*16.
__device__ __forceinline__ void gld16(const void* g, void* l) {
  __builtin_amdgcn_global_load_lds(
      (const __attribute__((address_space(1))) unsigned int*)g,
      (__attribute__((address_space(3))) unsigned int*)l,
      16, 0, 0);
}

// Read one MFMA fragment (8 bf16) from a swizzled LDS tile with 128-byte rows.
// Swizzle: phys_byte = row*128 + (kb ^ ((row&7)<<4))
__device__ __forceinline__ bf16x8 frag_ld(const u16* lds, int row, int kb) {
  int ph = row * 128 + (kb ^ ((row & 7) << 4));
  return *(const bf16x8*)((const char*)lds + ph);
}

// ---------------------------------------------------------------------------
// Weight transpose + fp32->bf16:  in [R][C] -> out [C][R]
// ---------------------------------------------------------------------------
__global__ __launch_bounds__(256) void k_prep(
    const float* __restrict__ W1, const float* __restrict__ W3,
    const float* __restrict__ W2, u16* __restrict__ W1T,
    u16* __restrict__ W3T, u16* __restrict__ W2T)
{
  __shared__ __align__(16) float td[64][68];
  const int z = blockIdx.z;
  const int mat = z >> 3, e = z & 7;
  const int R = (mat == 2) ? EDIM : DM;
  const int C = (mat == 2) ? DM : EDIM;
  const int r0 = blockIdx.x * 64, c0 = blockIdx.y * 64;
  if (r0 >= R || c0 >= C) return;
  const float* in = (mat == 0 ? W1 : mat == 1 ? W3 : W2) + (size_t)e * R * C;
  u16* out = (mat == 0 ? W1T : mat == 1 ? W3T : W2T) + (size_t)e * R * C;
  const int tid = threadIdx.x;
  {
    int rl = tid >> 2, cs = (tid & 3) * 16;
    const float* s = in + (size_t)(r0 + rl) * C + c0 + cs;
    #pragma unroll
    for (int i = 0; i < 16; i += 4) *(float4*)&td[rl][cs + i] = *(const float4*)(s + i);
  }
  __syncthreads();
  {
    int cl = tid >> 2, rs = (tid & 3) * 16;
    u16* d = out + (size_t)(c0 + cl) * R + r0 + rs;
    u16x8 o0, o1;
    #pragma unroll
    for (int i = 0; i < 8; ++i) {
      o0[i] = f2bf(td[rs + i][cl]);
      o1[i] = f2bf(td[rs + 8 + i][cl]);
    }
    *(u16x8*)d = o0;
    *(u16x8*)(d + 8) = o1;
  }
}

// ---------------------------------------------------------------------------
// Tokenize (NCHW -> token-major bf16) + fp32 router + top-2 + expert lists.
// 32 tokens per block (one b,h row), 1024 blocks, 256 threads.
// ---------------------------------------------------------------------------
__global__ __launch_bounds__(256) void k_tokrouter(
    const float* __restrict__ x, const float* __restrict__ Wr,
    u16* __restrict__ tokbf, int* __restrict__ cnt,
    int* __restrict__ toklist, float* __restrict__ gatelist)
{
  __shared__ float WrL[8][772];        // pad: stride 768 is bank-degenerate
  __shared__ float xL[64][33];         // [c][t], stride 33 -> <=2-way on all phases
  __shared__ float logitsL[32][8];
  __shared__ int cnt8[8];
  __shared__ int baseL[8];
  const int tid = threadIdx.x;
  const int t0 = blockIdx.x * 32;
  const int b = t0 >> 10;
  const int h = (t0 >> 5) & 31;
  const float* xb = x + (size_t)b * (DM * 1024) + h * 32;

  // stage Wr (fp32, full) into LDS
  for (int i = tid; i < 1536; i += 256) {
    int r = i / 192;                    // 192 float4 per expert row
    int c = (i - r * 192) * 4;
    *(float4*)&WrL[r][c] = ((const float4*)Wr)[i];
  }

  const int rt = tid >> 3;     // token 0..31 (router/tokbf phases)
  const int re = tid & 7;      // expert 0..7
  float lacc = 0.f;

  for (int cb = 0; cb < 12; ++cb) {
    const int c0 = cb * 64;
    __syncthreads();   // prev iter's xL reads done (also Wr staged, iter 0)
    #pragma unroll
    for (int it = 0; it < 2; ++it) {
      int idx = it * 256 + tid;
      int r = idx >> 3, cc = (idx & 7) * 4;
      float4 v = *(const float4*)(xb + (size_t)(c0 + r) * 1024 + cc);
      xL[r][cc] = v.x; xL[r][cc + 1] = v.y; xL[r][cc + 2] = v.z; xL[r][cc + 3] = v.w;
    }
    __syncthreads();
    // router accumulate (fp32)
    {
      const float* wr = &WrL[re][c0];
      #pragma unroll
      for (int c = 0; c < 64; ++c) lacc = fmaf(xL[c][rt], wr[c], lacc);
    }
    // token-major bf16 write (channels re*8..re*8+7)
    {
      u16x8 o;
      #pragma unroll
      for (int i = 0; i < 8; ++i) o[i] = f2bf(xL[re * 8 + i][rt]);
      *(u16x8*)(tokbf + (size_t)(t0 + rt) * DM + c0 + re * 8) = o;
    }
  }

  logitsL[rt][re] = lacc;
  if (tid < 8) cnt8[tid] = 0;
  __syncthreads();

  int e0 = -1, e1 = -1, lp0 = 0, lp1 = 0;
  float g0 = 0.f, g1 = 0.f;
  if (tid < 32) {
    float v0 = -1e30f, v1 = -1e30f;
    #pragma unroll
    for (int e = 0; e < 8; ++e) { float v = logitsL[tid][e]; if (v > v0) { v0 = v; e0 = e; } }
    #pragma unroll
    for (int e = 0; e < 8; ++e) {
      if (e == e0) continue;
      float v = logitsL[tid][e]; if (v > v1) { v1 = v; e1 = e; }
    }
    float w = expf(v1 - v0);            // v0 >= v1
    g0 = 1.f / (1.f + w);
    g1 = w / (1.f + w);
    lp0 = atomicAdd(&cnt8[e0], 1);
    lp1 = atomicAdd(&cnt8[e1], 1);
  }
  __syncthreads();
  if (tid < 8) baseL[tid] = atomicAdd(&cnt[tid], cnt8[tid]);
  __syncthreads();
  if (tid < 32) {
    int tg = t0 + tid;
    int p0 = baseL[e0] + lp0;
    int p1 = baseL[e1] + lp1;
    toklist[e0 * T_TOK + p0] = tg;              // k=0 slot
    gatelist[e0 * T_TOK + p0] = g0;
    toklist[e1 * T_TOK + p1] = tg | (1 << 16);  // k=1 slot
    gatelist[e1 * T_TOK + p1] = g1;
  }
}

__global__ void k_prefix(const int* __restrict__ cnt, int* __restrict__ offs) {
  if (threadIdx.x == 0) {
    int s = 0;
    for (int e = 0; e < NEXP; ++e) { offs[e] = s; s += cnt[e]; }
    offs[NEXP] = s;
  }
}

// ---------------------------------------------------------------------------
// Stage 1: h = silu(tok @ W1) * (tok @ W3). Tile 128x64, BK=64, 4 waves.
// Staging via global_load_lds (linear LDS dest, swizzle applied to source).
// ---------------------------------------------------------------------------
__global__ __launch_bounds__(256) void k_ffn1(
    const u16* __restrict__ tokbf, const u16* __restrict__ W1T,
    const u16* __restrict__ W3T, const int* __restrict__ cnt,
    const int* __restrict__ offs, const int* __restrict__ toklist,
    u16* __restrict__ hbuf)
{
  __shared__ __align__(16) u16 As[128 * 64];
  __shared__ __align__(16) u16 B1s[64 * 64];
  __shared__ __align__(16) u16 B3s[64 * 64];
  __shared__ int rowbaseL[128];
  const int e = blockIdx.z;
  const int count = cnt[e];
  const int start = blockIdx.x * 128;
  if (start >= count) return;
  const int n0 = blockIdx.y * 64;
  const int rows = min(128, count - start);
  const int tid = threadIdx.x;

  if (tid < 128) {
    int r = (tid < rows) ? tid : 0;
    rowbaseL[tid] = (toklist[e * T_TOK + start + r] & 0xFFFF) * DM;
  }
  __syncthreads();

  // kc-invariant staging addresses
  const int lrow = tid >> 3;                                   // 0..31
  const int swq = (((tid & 7) * 16) ^ ((lrow & 7) << 4)) >> 1; // u16 units
  const u16 *srcA[4], *srcB1[2], *srcB3[2];
  #pragma unroll
  for (int it = 0; it < 4; ++it)
    srcA[it] = tokbf + rowbaseL[it * 32 + lrow] + swq;
  #pragma unroll
  for (int it = 0; it < 2; ++it) {
    size_t wb = (size_t)(e * EDIM + n0 + it * 32 + lrow) * DM + swq;
    srcB1[it] = W1T + wb;
    srcB3[it] = W3T + wb;
  }

  const int w = tid >> 6, l = tid & 63;
  const int wm = (w >> 1) * 64, wn = (w & 1) * 32;
  const int lr = l & 15;
  const int lk = (l >> 4) * 16;

  f32x4 acc1[4][2], acc3[4][2];
  #pragma unroll
  for (int i = 0; i < 4; ++i)
    #pragma unroll
    for (int j = 0; j < 2; ++j) {
      acc1[i][j] = (f32x4){0.f, 0.f, 0.f, 0.f};
      acc3[i][j] = (f32x4){0.f, 0.f, 0.f, 0.f};
    }

  for (int kc = 0; kc < 12; ++kc) {
    const int ko = kc * 64;
    #pragma unroll
    for (int it = 0; it < 4; ++it)
      gld16(srcA[it] + ko, (char*)As + (it * 256 + tid) * 16);
    #pragma unroll
    for (int it = 0; it < 2; ++it) {
      gld16(srcB1[it] + ko, (char*)B1s + (it * 256 + tid) * 16);
      gld16(srcB3[it] + ko, (char*)B3s + (it * 256 + tid) * 16);
    }
    __syncthreads();
    #pragma unroll
    for (int kk = 0; kk < 2; ++kk) {
      const int kb = kk * 64 + lk;
      bf16x8 af[4], b1[2], b3[2];
      #pragma unroll
      for (int mf = 0; mf < 4; ++mf) af[mf] = frag_ld(As, wm + mf * 16 + lr, kb);
      #pragma unroll
      for (int nf = 0; nf < 2; ++nf) {
        b1[nf] = frag_ld(B1s, wn + nf * 16 + lr, kb);
        b3[nf] = frag_ld(B3s, wn + nf * 16 + lr, kb);
      }
      #pragma unroll
      for (int mf = 0; mf < 4; ++mf)
        #pragma unroll
        for (int nf = 0; nf < 2; ++nf) {
          acc1[mf][nf] = __builtin_amdgcn_mfma_f32_16x16x32_bf16(af[mf], b1[nf], acc1[mf][nf], 0, 0, 0);
          acc3[mf][nf] = __builtin_amdgcn_mfma_f32_16x16x32_bf16(af[mf], b3[nf], acc3[mf][nf], 0, 0, 0);
        }
    }
    __syncthreads();
  }

  const int rq = (l >> 4) * 4;
  const int abase = offs[e] + start;
  #pragma unroll
  for (int mf = 0; mf < 4; ++mf)
    #pragma unroll
    for (int nf = 0; nf < 2; ++nf)
      #pragma unroll
      for (int r = 0; r < 4; ++r) {
        int m = wm + mf * 16 + rq + r;
        if (m < rows) {
          float a = acc1[mf][nf][r];
          float hv = (a / (1.f + expf(-a))) * acc3[mf][nf][r];
          hbuf[(size_t)(abase + m) * EDIM + (n0 + wn + nf * 16 + lr)] = f2bf(hv);
        }
      }
}

// ---------------------------------------------------------------------------
// Stage 2: ypart[k][t][:] = gate * (h @ W2[e]). Tile 128x128, K=192, 4 waves.
// ---------------------------------------------------------------------------
__global__ __launch_bounds__(256) void k_ffn2(
    const u16* __restrict__ hbuf, const u16* __restrict__ W2T,
    const int* __restrict__ cnt, const int* __restrict__ offs,
    const int* __restrict__ toklist, const float* __restrict__ gatelist,
    u16* __restrict__ ypart)
{
  __shared__ __align__(16) u16 As[128 * 64];
  __shared__ __align__(16) u16 Bs[128 * 64];
  __shared__ int dstL[128];
  __shared__ float gL[128];
  const int e = blockIdx.z;
  const int count = cnt[e];
  const int start = blockIdx.x * 128;
  if (start >= count) return;
  const int n0 = blockIdx.y * 128;
  const int rows = min(128, count - start);
  const int tid = threadIdx.x;
  const int abase = offs[e] + start;

  if (tid < 128) {
    int r = (tid < rows) ? tid : 0;
    int entry = toklist[e * T_TOK + start + r];
    int t = entry & 0xFFFF, k = entry >> 16;
    dstL[tid] = (k * T_TOK + t) * DM;
    gL[tid] = gatelist[e * T_TOK + start + r];
  }
  __syncthreads();

  const int lrow = tid >> 3;
  const int swq = (((tid & 7) * 16) ^ ((lrow & 7) << 4)) >> 1;
  const u16 *srcA[4], *srcB[4];
  #pragma unroll
  for (int it = 0; it < 4; ++it) {
    int r = it * 32 + lrow;
    int rr = (r < rows) ? r : 0;
    srcA[it] = hbuf + (size_t)(abase + rr) * EDIM + swq;
    srcB[it] = W2T + (size_t)(e * DM + n0 + r) * EDIM + swq;
  }

  const int w = tid >> 6, l = tid & 63;
  const int wm = (w >> 1) * 64, wn = (w & 1) * 64;
  const int lr = l & 15;
  const int lk = (l >> 4) * 16;

  f32x4 acc[4][4];
  #pragma unroll
  for (int i = 0; i < 4; ++i)
    #pragma unroll
    for (int j = 0; j < 4; ++j) acc[i][j] = (f32x4){0.f, 0.f, 0.f, 0.f};

  for (int kc = 0; kc < 3; ++kc) {
    const int ko = kc * 64;
    #pragma unroll
    for (int it = 0; it < 4; ++it) {
      gld16(srcA[it] + ko, (char*)As + (it * 256 + tid) * 16);
      gld16(srcB[it] + ko, (char*)Bs + (it * 256 + tid) * 16);
    }
    __syncthreads();
    #pragma unroll
    for (int kk = 0; kk < 2; ++kk) {
      const int kb = kk * 64 + lk;
      bf16x8 af[4], bf_[4];
      #pragma unroll
      for (int mf = 0; mf < 4; ++mf) af[mf] = frag_ld(As, wm + mf * 16 + lr, kb);
      #pragma unroll
      for (int nf = 0; nf < 4; ++nf) bf_[nf] = frag_ld(Bs, wn + nf * 16 + lr, kb);
      #pragma unroll
      for (int mf = 0; mf < 4; ++mf)
        #pragma unroll
        for (int nf = 0; nf < 4; ++nf)
          acc[mf][nf] = __builtin_amdgcn_mfma_f32_16x16x32_bf16(af[mf], bf_[nf], acc[mf][nf], 0, 0, 0);
    }
    __syncthreads();
  }

  const int rq = (l >> 4) * 4;
  #pragma unroll
  for (int mf = 0; mf < 4; ++mf)
    #pragma unroll
    for (int nf = 0; nf < 4; ++nf)
      #pragma unroll
      for (int r = 0; r < 4; ++r) {
        int m = wm + mf * 16 + rq + r;
        if (m < rows) {
          float v = acc[mf][nf][r] * gL[m];
          ypart[(size_t)dstL[m] + (n0 + wn + nf * 16 + lr)] = f2bf(v);
        }
      }
}

// ---------------------------------------------------------------------------
// LN stats: per-token mean / rsqrt(var). 16 tokens/block, 2048 blocks.
// ---------------------------------------------------------------------------
__global__ __launch_bounds__(256) void k_stats(
    const u16* __restrict__ ypart, float* __restrict__ mu, float* __restrict__ rs)
{
  const int tid = threadIdx.x;
  const int t = blockIdx.x * 16 + (tid >> 4);
  const int j = tid & 15;
  const u16* y0 = ypart + (size_t)t * DM;
  const u16* y1 = y0 + (size_t)T_TOK * DM;
  float sum = 0.f, sq = 0.f;
  #pragma unroll
  for (int i = 0; i < 6; ++i) {
    int c = i * 128 + j * 8;
    u16x8 a = *(const u16x8*)(y0 + c);
    u16x8 b = *(const u16x8*)(y1 + c);
    #pragma unroll
    for (int q = 0; q < 8; ++q) {
      float v = bf2f(a[q]) + bf2f(b[q]);
      sum += v; sq += v * v;
    }
  }
  #pragma unroll
  for (int d = 1; d < 16; d <<= 1) { sum += __shfl_xor(sum, d); sq += __shfl_xor(sq, d); }
  if (j == 0) {
    float m = sum * (1.f / 768.f);
    float var = sq * (1.f / 768.f) - m * m;
    mu[t] = m;
    rs[t] = 1.f / sqrtf(var + 1e-5f);
  }
}

// ---------------------------------------------------------------------------
// LN apply + residual, NCHW write. Grid (512 token-blocks, 12 chan-blocks).
// ---------------------------------------------------------------------------
__global__ __launch_bounds__(256) void k_apply(
    const u16* __restrict__ ypart, const float* __restrict__ x,
    const float* __restrict__ gamma, const float* __restrict__ beta,
    const float* __restrict__ mu, const float* __restrict__ rs,
    float* __restrict__ out)
{
  __shared__ float lnT[64][65];
  const int tid = threadIdx.x;
  const int t0 = blockIdx.x * 64;
  const int c0 = blockIdx.y * 64;
  const int b = t0 >> 10;
  const int h0 = (t0 >> 5) & 31;
  const u16* y0 = ypart;
  const u16* y1 = ypart + (size_t)T_TOK * DM;
  {
    const int tl = tid >> 2, q = tid & 3;
    const size_t tbase = (size_t)(t0 + tl) * DM;
    const int c = c0 + q * 16;
    const float mu_ = mu[t0 + tl], rs_ = rs[t0 + tl];
    u16x8 a0 = *(const u16x8*)(y0 + tbase + c);
    u16x8 a1 = *(const u16x8*)(y0 + tbase + c + 8);
    u16x8 b0 = *(const u16x8*)(y1 + tbase + c);
    u16x8 b1 = *(const u16x8*)(y1 + tbase + c + 8);
    #pragma unroll
    for (int i = 0; i < 8; ++i) {
      float v = bf2f(a0[i]) + bf2f(b0[i]);
      lnT[q * 16 + i][tl] = (v - mu_) * rs_ * gamma[c + i] + beta[c + i];
      float u = bf2f(a1[i]) + bf2f(b1[i]);
      lnT[q * 16 + 8 + i][tl] = (u - mu_) * rs_ * gamma[c + 8 + i] + beta[c + 8 + i];
    }
  }
  __syncthreads();
  {
    int cl = tid >> 2, ts = (tid & 3) * 16;
    int c = c0 + cl;
    int hh = h0 + (ts >> 5), ww = ts & 31;
    size_t oidx = (((size_t)b * DM + c) * 32 + hh) * 32 + ww;
    #pragma unroll
    for (int i = 0; i < 16; i += 4) {
      float4 xv = *(const float4*)(x + oidx + i);
      float4 ov;
      ov.x = lnT[cl][ts + i + 0] + xv.x;
      ov.y = lnT[cl][ts + i + 1] + xv.y;
      ov.z = lnT[cl][ts + i + 2] + xv.z;
      ov.w = lnT[cl][ts + i + 3] + xv.w;
      *(float4*)(out + oidx + i) = ov;
    }
  }
}

// ---------------------------------------------------------------------------
// Workspace layout (all 256-aligned)
// ---------------------------------------------------------------------------
constexpr size_t OFF_TOK  = 0;
constexpr size_t OFF_W1T  = OFF_TOK + (size_t)T_TOK * DM * 2;
constexpr size_t OFF_W3T  = OFF_W1T + (size_t)NEXP * EDIM * DM * 2;
constexpr size_t OFF_W2T  = OFF_W3T + (size_t)NEXP * EDIM * DM * 2;
constexpr size_t OFF_H    = OFF_W2T + (size_t)NEXP * EDIM * DM * 2;
constexpr size_t OFF_YP   = OFF_H + (size_t)T_TOK * 2 * EDIM * 2;
constexpr size_t OFF_CNT  = OFF_YP + (size_t)2 * T_TOK * DM * 2;
constexpr size_t OFF_OFFS = OFF_CNT + 256;
constexpr size_t OFF_LIST = OFF_OFFS + 256;
constexpr size_t OFF_GATE = OFF_LIST + (size_t)NEXP * T_TOK * 4;
constexpr size_t OFF_MU   = OFF_GATE + (size_t)NEXP * T_TOK * 4;
constexpr size_t OFF_RS   = OFF_MU + (size_t)T_TOK * 4;

extern "C" void kernel_launch(void* const* d_in, const int* in_sizes, int n_in,
                              void* d_out, int out_size, void* d_ws, size_t ws_size,
                              hipStream_t stream) {
  const float* x     = (const float*)d_in[0];
  const float* Wr    = (const float*)d_in[1];
  const float* W1    = (const float*)d_in[2];
  const float* W3    = (const float*)d_in[3];
  const float* W2    = (const float*)d_in[4];
  const float* gamma = (const float*)d_in[5];
  const float* beta  = (const float*)d_in[6];
  float* out = (float*)d_out;
  char* ws = (char*)d_ws;

  u16* tokbf = (u16*)(ws + OFF_TOK);
  u16* W1T   = (u16*)(ws + OFF_W1T);
  u16* W3T   = (u16*)(ws + OFF_W3T);
  u16* W2T   = (u16*)(ws + OFF_W2T);
  u16* hbuf  = (u16*)(ws + OFF_H);
  u16* ypart = (u16*)(ws + OFF_YP);
  int* cnt   = (int*)(ws + OFF_CNT);
  int* offs  = (int*)(ws + OFF_OFFS);
  int* toklist = (int*)(ws + OFF_LIST);
  float* gatelist = (float*)(ws + OFF_GATE);
  float* muB = (float*)(ws + OFF_MU);
  float* rsB = (float*)(ws + OFF_RS);

  hipMemsetAsync(cnt, 0, 64, stream);
  hipLaunchKernelGGL(k_prep, dim3(12, 12, 24), dim3(256), 0, stream,
                     W1, W3, W2, W1T, W3T, W2T);
  hipLaunchKernelGGL(k_tokrouter, dim3(1024), dim3(256), 0, stream,
                     x, Wr, tokbf, cnt, toklist, gatelist);
  hipLaunchKernelGGL(k_prefix, dim3(1), dim3(64), 0, stream, cnt, offs);
  hipLaunchKernelGGL(k_ffn1, dim3(256, 3, 8), dim3(256), 0, stream,
                     tokbf, W1T, W3T, cnt, offs, toklist, hbuf);
  hipLaunchKernelGGL(k_ffn2, dim3(256, 6, 8), dim3(256), 0, stream,
                     hbuf, W2T, cnt, offs, toklist, gatelist, ypart);
  hipLaunchKernelGGL(k_stats, dim3(2048), dim3(256), 0, stream,
                     ypart, muB, rsB);
  hipLaunchKernelGGL(k_apply, dim3(512, 12), dim3(256), 0, stream,
                     ypart, x, gamma, beta, muB, rsB, out);
}